// Round 1
// baseline (230.550 us; speedup 1.0000x reference)
//
#include <hip/hip_runtime.h>

#define T_ 4
#define S_ 2048
#define D_ 768
#define SD_ (S_ * D_)          // 1572864
#define TSD_ (T_ * SD_)        // 6291456
#define H_ 12
#define HD_ 64
#define PLANE_BYTES 2359296u   // 4 planes * 768 * 768 int8 per weight matrix

typedef int int32x4 __attribute__((ext_vector_type(4)));

// async global->LDS, 16B per lane; LDS dest = wave-uniform base + lane*16
__device__ __forceinline__ void cp16(unsigned char* lds, const unsigned char* g) {
    __builtin_amdgcn_global_load_lds(
        (const __attribute__((address_space(1))) unsigned int*)g,
        (__attribute__((address_space(3))) unsigned int*)lds, 16, 0, 0);
}

// Fragment order for an Mx768 int8 matrix: chunk (m>>4, k>>6) is 1024B;
// within: (k>>4 &3)*256 + (m&15)*16 + (k&15). Wave A-frag = chunk + lane*16.
__device__ __forceinline__ size_t frag_addr(int m, int d) {
    return ((size_t)(m >> 4) * 12 + (d >> 6)) * 1024 +
           (size_t)(((d >> 4) & 3) * 256 + (m & 15) * 16 + (d & 15));
}

// ---------------------------------------------------------------------------
// 0) y<4: pack weight matrix y -> B-fragment order (LDS repack, coalesced).
//    y==4, x<384: if_node over x -> init spikes in fragment order.
//    y==4, 384<=x<432: zero the QKp presence accumulator (12288 words).
// ---------------------------------------------------------------------------
__global__ __launch_bounds__(256) void k_prep_all(const float* __restrict__ wq,
                                                  const float* __restrict__ wk,
                                                  const float* __restrict__ wv,
                                                  const float* __restrict__ wo,
                                                  const float* __restrict__ x,
                                                  unsigned char* __restrict__ Bp,
                                                  unsigned char* __restrict__ Sx,
                                                  unsigned int* __restrict__ QKp) {
    __shared__ unsigned char wl[4096];
    int tid = threadIdx.x;
    if (blockIdx.y < 4) {
        const float* W = (blockIdx.y == 0) ? wq : (blockIdx.y == 1) ? wk
                       : (blockIdx.y == 2) ? wv : wo;
        unsigned char* out = Bp + (size_t)blockIdx.y * PLANE_BYTES;
        int c = blockIdx.x;            // 0..575
        int kb = c % 12;
        int nbg = c / 12;
        int k_loc = tid >> 2;
        int n_base = (tid & 3) * 4;
        float4 w4 = *(const float4*)(
            W + (size_t)(kb * 64 + k_loc) * D_ + nbg * 16 + n_base);
        float wsv[4] = {w4.x, w4.y, w4.z, w4.w};
#pragma unroll
        for (int j = 0; j < 4; j++) {
            int n_loc = n_base + j;
            int u = (int)rintf(wsv[j] * 1073741824.0f);   // w * 2^30
#pragma unroll
            for (int p = 0; p < 4; p++) {
                wl[p * 1024 + (n_loc + 16 * (k_loc >> 4)) * 16 + (k_loc & 15)] =
                    (unsigned char)(u & 255);
                u = (u + 128) >> 8;                        // balanced peel
            }
        }
        __syncthreads();
        int p = tid >> 6;
        int lane = tid & 63;
        uint4 val = *(const uint4*)&wl[p * 1024 + lane * 16];
        *(uint4*)(out + (size_t)((p * 48 + nbg) * 12 + kb) * 1024 + lane * 16) =
            val;
    } else {
        if (blockIdx.x >= 384) {
            if (blockIdx.x < 432) {
                int idx = (blockIdx.x - 384) * 256 + tid;   // < 12288
                QKp[idx] = 0u;
            }
            return;
        }
        int gid = blockIdx.x * 256 + tid;      // 98304 threads
        int s = gid / 48;
        int d0 = (gid % 48) * 16;
        double v[16];
#pragma unroll
        for (int j = 0; j < 16; j++) v[j] = 0.0;
#pragma unroll
        for (int t = 0; t < T_; t++) {
            union { uint4 u; unsigned char b[16]; } sp;
#pragma unroll
            for (int q = 0; q < 4; q++) {
                float4 xt = *(const float4*)(
                    x + (size_t)t * SD_ + (size_t)s * D_ + d0 + q * 4);
                float xs[4] = {xt.x, xt.y, xt.z, xt.w};
#pragma unroll
                for (int j = 0; j < 4; j++) {
                    int jj = q * 4 + j;
                    v[jj] += (double)xs[j];
                    unsigned char ss = (v[jj] >= 1.0) ? 1 : 0;
                    sp.b[jj] = ss;
                    if (ss) v[jj] = 0.0;
                }
            }
            *(uint4*)(Sx + frag_addr(t * S_ + s, d0)) = sp.u;
        }
    }
}

// ---------------------------------------------------------------------------
// 2) i8 MFMA GEMM, exact fixed-point. Counted-vmcnt double-buffer pipeline:
//    BK=64, A AND B staged via global_load_lds (6 cp16/wave/stage), so the
//    loop's only VMEM is the stage -> s_waitcnt vmcnt(6) keeps the newest
//    stage in flight across a 2-iteration window; no vmcnt(0) drain in the
//    main loop (T3+T4). setprio(1) around the MFMA cluster (T5).
//    Tile 128M x 64N; 4 waves 2x2; wave 64M x 32N x 4 planes (128 AGPR acc).
// ---------------------------------------------------------------------------
#define GBUF 24576   // per k-block: A 8KB + B 16KB

__global__ __launch_bounds__(256, 2) void k_gemm_i8(
    const unsigned char* __restrict__ A,   // fragment-order spikes
    const unsigned char* __restrict__ Bp,  // packed digit planes (frag order)
    const unsigned int* __restrict__ Mp,   // QKp [16][4][192] words or nullptr
    float* __restrict__ C0, float* __restrict__ C1, float* __restrict__ C2,
    int bzoff) {
    int z = blockIdx.z;
    const unsigned char* B = Bp + (size_t)(bzoff + z) * PLANE_BYTES;
    float* C = (z == 0) ? C0 : (z == 1) ? C1 : C2;

    __shared__ __align__(16) unsigned char lds[2 * GBUF];
    __shared__ __align__(16) unsigned int maskw[192];

    int tid = threadIdx.x;
    int lane = tid & 63;
    int w = tid >> 6;                 // wave 0..3
    int wm = w >> 1;                  // 0..1
    int wn = w & 1;                   // 0..1
    int row0 = blockIdx.x * 128;
    int tI = row0 >> 11;              // uniform t for this block
    int n0 = blockIdx.y * 64;
    int nbg0 = blockIdx.y * 4;
    int col = lane & 15;
    int quad = lane >> 4;

    const unsigned char* Ag = A + (size_t)(row0 >> 4) * 12 * 1024 + lane * 16;
    const unsigned char* Bg = B + lane * 16;

    // stage k-block kb (64 K) into buffer buf: 8x1KB A chunks + 16x1KB B
    // chunks, 6 cp16 per thread, wave-uniform LDS bases.
    auto stage = [&](int buf, int kb) {
        unsigned char* dst = lds + buf * GBUF;
#pragma unroll
        for (int i = 0; i < 2; i++) {
            int mc = w * 2 + i;
            cp16(dst + mc * 1024, Ag + (size_t)(mc * 12 + kb) * 1024);
        }
#pragma unroll
        for (int qi = 0; qi < 4; qi++) {
            int q = w * 4 + qi;       // chunk id: p = q>>2, nb = q&3
            int p = q >> 2;
            int nb = q & 3;
            cp16(dst + 8192 + q * 1024,
                 Bg + (size_t)((p * 48 + nbg0 + nb) * 12 + kb) * 1024);
        }
    };

    int32x4 zerov = {0, 0, 0, 0};
    int32x4 acc[4][2][4];             // [mb][nb][p]
#pragma unroll
    for (int mb = 0; mb < 4; mb++)
#pragma unroll
        for (int nb = 0; nb < 2; nb++)
#pragma unroll
            for (int p = 0; p < 4; p++) acc[mb][nb][p] = zerov;

    stage(0, 0);
    stage(1, 1);
    if (Mp && tid < 192) {
        unsigned int m = 0;
#pragma unroll
        for (int c = 0; c < 16; c++) m |= Mp[c * 768 + tI * 192 + tid];
        maskw[tid] = m;               // bytes in {0,1}
    }
    asm volatile("s_waitcnt vmcnt(0)" ::: "memory");  // buf0+buf1 landed
    __syncthreads();

    // One k-block step. Steady state at entry: stage(kb) + stage(kb+1)
    // outstanding (12) -> vmcnt(6) retires stage(kb); barrier makes buf[cur]
    // valid for all waves. After compute: lgkmcnt(0)+barrier = all waves'
    // ds_reads of buf[cur] complete -> safe to restage it with kb+2.
    auto kstep = [&](int kb, int cur, bool dostage, bool last) {
        if (last) asm volatile("s_waitcnt vmcnt(0)" ::: "memory");
        else      asm volatile("s_waitcnt vmcnt(6)" ::: "memory");
        __builtin_amdgcn_sched_barrier(0);
        __builtin_amdgcn_s_barrier();
        asm volatile("" ::: "memory");
        __builtin_amdgcn_sched_barrier(0);
        const unsigned char* Ab = lds + cur * GBUF;
        const unsigned char* Bb = Ab + 8192;
        __builtin_amdgcn_s_setprio(1);
        int32x4 af[4];
#pragma unroll
        for (int mb = 0; mb < 4; mb++)
            af[mb] = *(const int32x4*)(Ab + (wm * 4 + mb) * 1024 + lane * 16);
        if (Mp) {
            int32x4 mv = *(const int32x4*)((const unsigned char*)maskw +
                                           kb * 64 + quad * 16);
#pragma unroll
            for (int mb = 0; mb < 4; mb++) af[mb] &= mv;
        }
#pragma unroll
        for (int p = 0; p < 4; p++)
#pragma unroll
            for (int nb = 0; nb < 2; nb++) {
                int32x4 bf = *(const int32x4*)(
                    Bb + (p * 4 + wn * 2 + nb) * 1024 + lane * 16);
#pragma unroll
                for (int mb = 0; mb < 4; mb++)
                    acc[mb][nb][p] = __builtin_amdgcn_mfma_i32_16x16x64_i8(
                        af[mb], bf, acc[mb][nb][p], 0, 0, 0);
            }
        __builtin_amdgcn_s_setprio(0);
        asm volatile("s_waitcnt lgkmcnt(0)" ::: "memory");
        __builtin_amdgcn_sched_barrier(0);
        __builtin_amdgcn_s_barrier();
        asm volatile("" ::: "memory");
        __builtin_amdgcn_sched_barrier(0);
        if (dostage) stage(cur, kb + 2);
    };

    for (int kb2 = 0; kb2 < 5; kb2++) {
        kstep(2 * kb2, 0, true, false);
        kstep(2 * kb2 + 1, 1, true, false);
    }
    kstep(10, 0, false, false);
    kstep(11, 1, false, true);

#pragma unroll
    for (int mb = 0; mb < 4; mb++)
#pragma unroll
        for (int nb = 0; nb < 2; nb++)
#pragma unroll
            for (int r = 0; r < 4; r++) {
                // exact: digits < 2^17, products/sums exact in double
                double td = (double)acc[mb][nb][0][r]
                          + 256.0 * (double)acc[mb][nb][1][r]
                          + 65536.0 * (double)acc[mb][nb][2][r]
                          + 16777216.0 * (double)acc[mb][nb][3][r];
                float v = (float)(td * (1.0 / 1073741824.0));
                int rr = row0 + wm * 64 + mb * 16 + quad * 4 + r;
                int cc = n0 + wn * 32 + nb * 16 + col;
                C[(size_t)rr * D_ + cc] = v;
            }
}

// ---------------------------------------------------------------------------
// 3) Fused BN + IF for Q,K,V in ONE block per s. float4 loads, single merged
//    reduction for all 6 stats (3 barriers total). Q/K spikes never leave the
//    block: q&k presence bytes are atomicOr'd packed into QKp[s%16] copies.
//    V spikes written int8 fragment-order.
// ---------------------------------------------------------------------------
__global__ __launch_bounds__(256) void k_bnif_qk(const float* __restrict__ Qf,
                                                 const float* __restrict__ Kf,
                                                 const float* __restrict__ Vf,
                                                 unsigned char* __restrict__ Vs,
                                                 unsigned int* __restrict__ QKp) {
    int s = blockIdx.x;
    __shared__ float buf[3][T_][D_];          // 36 KB
    __shared__ double red[4][6];
    __shared__ unsigned char spkV[T_ * D_];   // 3 KB
    __shared__ unsigned char spkA[T_ * D_];   // 3 KB (q & k)
    __shared__ double stats[3][2];            // mean, rstd per tensor

    int tid = threadIdx.x;
    int lane = tid & 63, wv = tid >> 6;
    const float* Xs[3] = {Qf, Kf, Vf};
    double sum[3] = {0.0, 0.0, 0.0}, sumsq[3] = {0.0, 0.0, 0.0};
#pragma unroll
    for (int y = 0; y < 3; y++) {
#pragma unroll
        for (int i = 0; i < 3; i++) {
            int idx = i * 256 + tid;          // 0..767 float4 chunks
            int t = idx / 192;
            int c = idx - t * 192;
            float4 v = *(const float4*)(
                Xs[y] + (size_t)t * SD_ + (size_t)s * D_ + c * 4);
            *(float4*)&buf[y][t][c * 4] = v;
            sum[y] += ((double)v.x + (double)v.y) +
                      ((double)v.z + (double)v.w);
            sumsq[y] += ((double)v.x * v.x + (double)v.y * v.y) +
                        ((double)v.z * v.z + (double)v.w * v.w);
        }
    }
#pragma unroll
    for (int off = 32; off > 0; off >>= 1) {
#pragma unroll
        for (int y = 0; y < 3; y++) {
            sum[y] += __shfl_down(sum[y], off);
            sumsq[y] += __shfl_down(sumsq[y], off);
        }
    }
    if (lane == 0) {
#pragma unroll
        for (int y = 0; y < 3; y++) {
            red[wv][y] = sum[y];
            red[wv][3 + y] = sumsq[y];
        }
    }
    __syncthreads();
    if (tid < 3) {
        double s4 = red[0][tid] + red[1][tid] + red[2][tid] + red[3][tid];
        double q4 = red[0][3 + tid] + red[1][3 + tid] + red[2][3 + tid] +
                    red[3][3 + tid];
        double mean = s4 / 3072.0;
        double var = q4 / 3072.0 - mean * mean;
        stats[tid][0] = mean;
        stats[tid][1] = 1.0 / sqrt(var + 1e-5);
    }
    __syncthreads();

    for (int d = tid; d < D_; d += 256) {
        unsigned char qs[T_], ks[T_];
#pragma unroll
        for (int y = 0; y < 3; y++) {
            double mean = stats[y][0], rstd = stats[y][1];
            double v = 0.0;
#pragma unroll
            for (int t = 0; t < T_; t++) {
                double xn = ((double)buf[y][t][d] - mean) * rstd;
                v += xn;
                unsigned char sp = (v >= 1.0) ? 1 : 0;
                if (y == 0) qs[t] = sp;
                else if (y == 1) ks[t] = sp;
                else spkV[t * D_ + d] = sp;
                if (sp) v = 0.0;
            }
        }
#pragma unroll
        for (int t = 0; t < T_; t++) spkA[t * D_ + d] = qs[t] & ks[t];
    }
    __syncthreads();

    if (tid < 192) {
        // V spikes -> fragment order (16-byte granules)
        int tt = tid / 48, gg = tid % 48;
        uint4 val = *(const uint4*)&spkV[tt * D_ + gg * 16];
        size_t dst = ((size_t)(tt * 128 + (s >> 4)) * 12 + (gg >> 2)) * 1024 +
                     (size_t)((gg & 3) * 256 + (s & 15) * 16);
        *(uint4*)(Vs + dst) = val;
        // q&k presence -> privatized OR accumulator (packed bytes)
        unsigned int* dstq = QKp + (s & 15) * 768;
#pragma unroll
        for (int t = 0; t < T_; t++) {
            unsigned int word = *(const unsigned int*)&spkA[t * D_ + tid * 4];
            if (word) atomicOr(dstq + t * 192 + tid, word);
        }
    }
}

// ---------------------------------------------------------------------------
// 6) Final BatchNorm1d (fp64 stats), register-resident, float4 in/out.
// ---------------------------------------------------------------------------
__global__ __launch_bounds__(256) void k_bn_out(const float* __restrict__ Xin,
                                                float* __restrict__ out) {
    int s = blockIdx.x;
    __shared__ double red[4][2];
    __shared__ double st[2];
    int tid = threadIdx.x;
    int lane = tid & 63, wv = tid >> 6;
    float4 vv[3];
    double sum = 0.0, sumsq = 0.0;
#pragma unroll
    for (int i = 0; i < 3; i++) {
        int idx = i * 256 + tid;
        int t = idx / 192, c = idx - t * 192;
        float4 v = *(const float4*)(
            Xin + (size_t)t * SD_ + (size_t)s * D_ + c * 4);
        vv[i] = v;
        sum += ((double)v.x + (double)v.y) + ((double)v.z + (double)v.w);
        sumsq += ((double)v.x * v.x + (double)v.y * v.y) +
                 ((double)v.z * v.z + (double)v.w * v.w);
    }
#pragma unroll
    for (int off = 32; off > 0; off >>= 1) {
        sum += __shfl_down(sum, off);
        sumsq += __shfl_down(sumsq, off);
    }
    if (lane == 0) { red[wv][0] = sum; red[wv][1] = sumsq; }
    __syncthreads();
    if (tid == 0) {
        double s4 = red[0][0] + red[1][0] + red[2][0] + red[3][0];
        double q4 = red[0][1] + red[1][1] + red[2][1] + red[3][1];
        double mean = s4 / 3072.0;
        double var = q4 / 3072.0 - mean * mean;
        st[0] = mean;
        st[1] = 1.0 / sqrt(var + 1e-5);
    }
    __syncthreads();
    double mean = st[0], rstd = st[1];
#pragma unroll
    for (int i = 0; i < 3; i++) {
        int idx = i * 256 + tid;
        int t = idx / 192, c = idx - t * 192;
        float4 o;
        o.x = (float)(((double)vv[i].x - mean) * rstd);
        o.y = (float)(((double)vv[i].y - mean) * rstd);
        o.z = (float)(((double)vv[i].z - mean) * rstd);
        o.w = (float)(((double)vv[i].w - mean) * rstd);
        *(float4*)(out + (size_t)t * SD_ + (size_t)s * D_ + c * 4) = o;
    }
}

// ---------------------------------------------------------------------------
extern "C" void kernel_launch(void* const* d_in, const int* in_sizes, int n_in,
                              void* d_out, int out_size, void* d_ws,
                              size_t ws_size, hipStream_t stream) {
    const float* x  = (const float*)d_in[0];
    const float* wq = (const float*)d_in[1];
    const float* wk = (const float*)d_in[2];
    const float* wv = (const float*)d_in[3];
    const float* wo = (const float*)d_in[4];
    float* out = (float*)d_out;

    float* ws  = (float*)d_ws;
    float* Qf  = ws;                         // pre-BN Q, then GEMM2 out
    float* Kf  = ws + (size_t)TSD_;
    float* Vf  = ws + (size_t)2 * TSD_;
    unsigned int* QKp = (unsigned int*)(ws + (size_t)3 * TSD_);  // 12288 words
    unsigned char* Sx = (unsigned char*)(QKp + 12288);  // init spikes (frag)
    unsigned char* Vs = Sx + (size_t)TSD_;
    unsigned char* Bp = Vs + (size_t)TSD_;   // packed weights, 9.4 MB

    // 0) pack weights + init spikes + zero QKp
    k_prep_all<<<dim3(576, 5), 256, 0, stream>>>(wq, wk, wv, wo, x, Bp, Sx,
                                                 QKp);
    // 1) Q/K/V GEMMs (counted-vmcnt pipelined, A+B staged via LDS)
    k_gemm_i8<<<dim3(64, 12, 3), 256, 0, stream>>>(Sx, Bp, nullptr,
                                                   Qf, Kf, Vf, 0);
    // 2) BN + IF for Q,K,V + q&k presence accumulation (one block per s)
    k_bnif_qk<<<S_, 256, 0, stream>>>(Qf, Kf, Vf, Vs, QKp);
    // 3) out_pre = (Vs & mask) @ wo -> Qf  (mask OR-reduced in prologue)
    k_gemm_i8<<<dim3(64, 12, 1), 256, 0, stream>>>(Vs, Bp, QKp, Qf, Qf, Qf, 3);
    // 4) final BN -> d_out
    k_bn_out<<<S_, 256, 0, stream>>>(Qf, out);
}

// Round 2
// 199.108 us; speedup vs baseline: 1.1579x; 1.1579x over previous
//
#include <hip/hip_runtime.h>

#define T_ 4
#define S_ 2048
#define D_ 768
#define SD_ (S_ * D_)          // 1572864
#define TSD_ (T_ * SD_)        // 6291456
#define H_ 12
#define HD_ 64
#define PLANE_BYTES 2359296u   // 4 planes * 768 * 768 int8 per weight matrix

typedef int int32x4 __attribute__((ext_vector_type(4)));

// async global->LDS, 16B per lane; LDS dest = wave-uniform base + lane*16
__device__ __forceinline__ void cp16(unsigned char* lds, const unsigned char* g) {
    __builtin_amdgcn_global_load_lds(
        (const __attribute__((address_space(1))) unsigned int*)g,
        (__attribute__((address_space(3))) unsigned int*)lds, 16, 0, 0);
}

// Fragment order for an Mx768 int8 matrix: chunk (m>>4, k>>6) is 1024B;
// within: (k>>4 &3)*256 + (m&15)*16 + (k&15). Wave A-frag = chunk + lane*16.
__device__ __forceinline__ size_t frag_addr(int m, int d) {
    return ((size_t)(m >> 4) * 12 + (d >> 6)) * 1024 +
           (size_t)(((d >> 4) & 3) * 256 + (m & 15) * 16 + (d & 15));
}

// ---------------------------------------------------------------------------
// 0) y<4: pack weight matrix y -> B-fragment order (LDS repack, coalesced).
//    y==4, x<384: if_node over x -> init spikes in fragment order.
//    y==4, 384<=x<432: zero the QKp presence accumulator (12288 words).
// ---------------------------------------------------------------------------
__global__ __launch_bounds__(256) void k_prep_all(const float* __restrict__ wq,
                                                  const float* __restrict__ wk,
                                                  const float* __restrict__ wv,
                                                  const float* __restrict__ wo,
                                                  const float* __restrict__ x,
                                                  unsigned char* __restrict__ Bp,
                                                  unsigned char* __restrict__ Sx,
                                                  unsigned int* __restrict__ QKp) {
    __shared__ unsigned char wl[4096];
    int tid = threadIdx.x;
    if (blockIdx.y < 4) {
        const float* W = (blockIdx.y == 0) ? wq : (blockIdx.y == 1) ? wk
                       : (blockIdx.y == 2) ? wv : wo;
        unsigned char* out = Bp + (size_t)blockIdx.y * PLANE_BYTES;
        int c = blockIdx.x;            // 0..575
        int kb = c % 12;
        int nbg = c / 12;
        int k_loc = tid >> 2;
        int n_base = (tid & 3) * 4;
        float4 w4 = *(const float4*)(
            W + (size_t)(kb * 64 + k_loc) * D_ + nbg * 16 + n_base);
        float wsv[4] = {w4.x, w4.y, w4.z, w4.w};
#pragma unroll
        for (int j = 0; j < 4; j++) {
            int n_loc = n_base + j;
            int u = (int)rintf(wsv[j] * 1073741824.0f);   // w * 2^30
#pragma unroll
            for (int p = 0; p < 4; p++) {
                wl[p * 1024 + (n_loc + 16 * (k_loc >> 4)) * 16 + (k_loc & 15)] =
                    (unsigned char)(u & 255);
                u = (u + 128) >> 8;                        // balanced peel
            }
        }
        __syncthreads();
        int p = tid >> 6;
        int lane = tid & 63;
        uint4 val = *(const uint4*)&wl[p * 1024 + lane * 16];
        *(uint4*)(out + (size_t)((p * 48 + nbg) * 12 + kb) * 1024 + lane * 16) =
            val;
    } else {
        if (blockIdx.x >= 384) {
            if (blockIdx.x < 432) {
                int idx = (blockIdx.x - 384) * 256 + tid;   // < 12288
                QKp[idx] = 0u;
            }
            return;
        }
        int gid = blockIdx.x * 256 + tid;      // 98304 threads
        int s = gid / 48;
        int d0 = (gid % 48) * 16;
        double v[16];
#pragma unroll
        for (int j = 0; j < 16; j++) v[j] = 0.0;
#pragma unroll
        for (int t = 0; t < T_; t++) {
            union { uint4 u; unsigned char b[16]; } sp;
#pragma unroll
            for (int q = 0; q < 4; q++) {
                float4 xt = *(const float4*)(
                    x + (size_t)t * SD_ + (size_t)s * D_ + d0 + q * 4);
                float xs[4] = {xt.x, xt.y, xt.z, xt.w};
#pragma unroll
                for (int j = 0; j < 4; j++) {
                    int jj = q * 4 + j;
                    v[jj] += (double)xs[j];
                    unsigned char ss = (v[jj] >= 1.0) ? 1 : 0;
                    sp.b[jj] = ss;
                    if (ss) v[jj] = 0.0;
                }
            }
            *(uint4*)(Sx + frag_addr(t * S_ + s, d0)) = sp.u;
        }
    }
}

// ---------------------------------------------------------------------------
// 2) i8 MFMA GEMM, exact fixed-point. B LDS-staged with BK=128 (2 k-blocks
//    per barrier, 2x32KB dbuf); A streamed from global fragment order with
//    register rotation. Optional mask: Mp = QKp presence words; prologue
//    OR-reduces 16 copies into an LDS byte mask for this block's t.
//    Tile 128M x 64N; 4 waves 2x2; wave 64M x 32N x 4 planes (128 AGPR acc).
//    NOTE (R1 post-mortem): the counted-vmcnt BK=64 rewrite regressed
//    57->92.5 us (restage-after-consume narrows the prefetch window to ONE
//    kstep < L2-miss latency, and doubles barrier count). This stage-at-
//    iteration-start BK=128 form is the verified-fast structure; keep it.
// ---------------------------------------------------------------------------
__global__ __launch_bounds__(256, 2) void k_gemm_i8(
    const unsigned char* __restrict__ A,   // fragment-order spikes
    const unsigned char* __restrict__ Bp,  // packed digit planes (frag order)
    const unsigned int* __restrict__ Mp,   // QKp [16][4][192] words or nullptr
    float* __restrict__ C0, float* __restrict__ C1, float* __restrict__ C2,
    int bzoff) {
    int z = blockIdx.z;
    const unsigned char* B = Bp + (size_t)(bzoff + z) * PLANE_BYTES;
    float* C = (z == 0) ? C0 : (z == 1) ? C1 : C2;

    __shared__ __align__(16) unsigned char bsm[2 * 32768];
    __shared__ __align__(16) unsigned int maskw[192];

    int tid = threadIdx.x;
    int lane = tid & 63;
    int w = tid >> 6;                 // wave 0..3
    int wm = w >> 1;                  // 0..1
    int wn = w & 1;                   // 0..1
    int row0 = blockIdx.x * 128;
    int tI = row0 >> 11;              // uniform t for this block
    int n0 = blockIdx.y * 64;
    int nbg0 = blockIdx.y * 4;
    int col = lane & 15;
    int quad = lane >> 4;

    int32x4 zerov = {0, 0, 0, 0};
    int32x4 acc[4][2][4];             // [mb][nb][p]
#pragma unroll
    for (int mb = 0; mb < 4; mb++)
#pragma unroll
        for (int nb = 0; nb < 2; nb++)
#pragma unroll
            for (int p = 0; p < 4; p++) acc[mb][nb][p] = zerov;

    const unsigned char* Ab =
        A + (size_t)((row0 >> 4) + wm * 4) * 12 * 1024 + lane * 16;

    // stage k-blocks 2*kb2 and 2*kb2+1 into buffer buf
    auto stageB = [&](int buf, int kb2) {
        unsigned char* bb = bsm + buf * 32768;
#pragma unroll
        for (int kk = 0; kk < 2; kk++)
#pragma unroll
            for (int qi = 0; qi < 4; qi++) {
                int q = w * 4 + qi;       // chunk id: p = q>>2, nb = q&3
                int p = q >> 2, nb = q & 3;
                cp16(bb + kk * 16384 + q * 1024,
                     B + (size_t)((p * 48 + nbg0 + nb) * 12 + 2 * kb2 + kk) *
                             1024 + lane * 16);
            }
    };

    stageB(0, 0);
    if (Mp && tid < 192) {
        unsigned int m = 0;
#pragma unroll
        for (int c = 0; c < 16; c++) m |= Mp[c * 768 + tI * 192 + tid];
        maskw[tid] = m;               // bytes in {0,1}
    }
    int32x4 a[2][4];
#pragma unroll
    for (int mb = 0; mb < 4; mb++)
        a[0][mb] = *(const int32x4*)(Ab + (size_t)(mb * 12) * 1024);
    __syncthreads();

    for (int kb2 = 0; kb2 < 6; kb2++) {
        int cur = kb2 & 1;
        if (kb2 < 5) stageB(1 - cur, kb2 + 1);
#pragma unroll
        for (int kbh = 0; kbh < 2; kbh++) {
            int kb = kb2 * 2 + kbh;
            if (kb < 11) {
#pragma unroll
                for (int mb = 0; mb < 4; mb++)
                    a[(kb + 1) & 1][mb] = *(const int32x4*)(
                        Ab + (size_t)(mb * 12 + kb + 1) * 1024);
            }
            int32x4 af[4];
#pragma unroll
            for (int mb = 0; mb < 4; mb++) af[mb] = a[kb & 1][mb];
            if (Mp) {
                int32x4 mv = *(const int32x4*)(
                    (const unsigned char*)maskw + kb * 64 + quad * 16);
#pragma unroll
                for (int mb = 0; mb < 4; mb++) af[mb] &= mv;
            }
            const unsigned char* bb = bsm + cur * 32768 + kbh * 16384;
#pragma unroll
            for (int p = 0; p < 4; p++)
#pragma unroll
                for (int nb = 0; nb < 2; nb++) {
                    int32x4 bf = *(const int32x4*)(
                        bb + (size_t)(p * 4 + wn * 2 + nb) * 1024 + lane * 16);
#pragma unroll
                    for (int mb = 0; mb < 4; mb++)
                        acc[mb][nb][p] = __builtin_amdgcn_mfma_i32_16x16x64_i8(
                            af[mb], bf, acc[mb][nb][p], 0, 0, 0);
                }
        }
        __syncthreads();
    }

#pragma unroll
    for (int mb = 0; mb < 4; mb++)
#pragma unroll
        for (int nb = 0; nb < 2; nb++)
#pragma unroll
            for (int r = 0; r < 4; r++) {
                // exact: digits < 2^17, products/sums exact in double
                double td = (double)acc[mb][nb][0][r]
                          + 256.0 * (double)acc[mb][nb][1][r]
                          + 65536.0 * (double)acc[mb][nb][2][r]
                          + 16777216.0 * (double)acc[mb][nb][3][r];
                float v = (float)(td * (1.0 / 1073741824.0));
                int rr = row0 + wm * 64 + mb * 16 + quad * 4 + r;
                int cc = n0 + wn * 32 + nb * 16 + col;
                C[(size_t)rr * D_ + cc] = v;
            }
}

// ---------------------------------------------------------------------------
// 3) Fused BN + IF for Q,K,V in ONE block per s. float4 loads, single merged
//    reduction for all 6 stats (3 barriers total). Q/K spikes never leave the
//    block: q&k presence bytes are atomicOr'd packed into QKp[s%16] copies.
//    V spikes written int8 fragment-order.  (R1: -~30 us vs scalar version.)
// ---------------------------------------------------------------------------
__global__ __launch_bounds__(256) void k_bnif_qk(const float* __restrict__ Qf,
                                                 const float* __restrict__ Kf,
                                                 const float* __restrict__ Vf,
                                                 unsigned char* __restrict__ Vs,
                                                 unsigned int* __restrict__ QKp) {
    int s = blockIdx.x;
    __shared__ float buf[3][T_][D_];          // 36 KB
    __shared__ double red[4][6];
    __shared__ unsigned char spkV[T_ * D_];   // 3 KB
    __shared__ unsigned char spkA[T_ * D_];   // 3 KB (q & k)
    __shared__ double stats[3][2];            // mean, rstd per tensor

    int tid = threadIdx.x;
    int lane = tid & 63, wv = tid >> 6;
    const float* Xs[3] = {Qf, Kf, Vf};
    double sum[3] = {0.0, 0.0, 0.0}, sumsq[3] = {0.0, 0.0, 0.0};
#pragma unroll
    for (int y = 0; y < 3; y++) {
#pragma unroll
        for (int i = 0; i < 3; i++) {
            int idx = i * 256 + tid;          // 0..767 float4 chunks
            int t = idx / 192;
            int c = idx - t * 192;
            float4 v = *(const float4*)(
                Xs[y] + (size_t)t * SD_ + (size_t)s * D_ + c * 4);
            *(float4*)&buf[y][t][c * 4] = v;
            sum[y] += ((double)v.x + (double)v.y) +
                      ((double)v.z + (double)v.w);
            sumsq[y] += ((double)v.x * v.x + (double)v.y * v.y) +
                        ((double)v.z * v.z + (double)v.w * v.w);
        }
    }
#pragma unroll
    for (int off = 32; off > 0; off >>= 1) {
#pragma unroll
        for (int y = 0; y < 3; y++) {
            sum[y] += __shfl_down(sum[y], off);
            sumsq[y] += __shfl_down(sumsq[y], off);
        }
    }
    if (lane == 0) {
#pragma unroll
        for (int y = 0; y < 3; y++) {
            red[wv][y] = sum[y];
            red[wv][3 + y] = sumsq[y];
        }
    }
    __syncthreads();
    if (tid < 3) {
        double s4 = red[0][tid] + red[1][tid] + red[2][tid] + red[3][tid];
        double q4 = red[0][3 + tid] + red[1][3 + tid] + red[2][3 + tid] +
                    red[3][3 + tid];
        double mean = s4 / 3072.0;
        double var = q4 / 3072.0 - mean * mean;
        stats[tid][0] = mean;
        stats[tid][1] = 1.0 / sqrt(var + 1e-5);
    }
    __syncthreads();

    for (int d = tid; d < D_; d += 256) {
        unsigned char qs[T_], ks[T_];
#pragma unroll
        for (int y = 0; y < 3; y++) {
            double mean = stats[y][0], rstd = stats[y][1];
            double v = 0.0;
#pragma unroll
            for (int t = 0; t < T_; t++) {
                double xn = ((double)buf[y][t][d] - mean) * rstd;
                v += xn;
                unsigned char sp = (v >= 1.0) ? 1 : 0;
                if (y == 0) qs[t] = sp;
                else if (y == 1) ks[t] = sp;
                else spkV[t * D_ + d] = sp;
                if (sp) v = 0.0;
            }
        }
#pragma unroll
        for (int t = 0; t < T_; t++) spkA[t * D_ + d] = qs[t] & ks[t];
    }
    __syncthreads();

    if (tid < 192) {
        // V spikes -> fragment order (16-byte granules)
        int tt = tid / 48, gg = tid % 48;
        uint4 val = *(const uint4*)&spkV[tt * D_ + gg * 16];
        size_t dst = ((size_t)(tt * 128 + (s >> 4)) * 12 + (gg >> 2)) * 1024 +
                     (size_t)((gg & 3) * 256 + (s & 15) * 16);
        *(uint4*)(Vs + dst) = val;
        // q&k presence -> privatized OR accumulator (packed bytes)
        unsigned int* dstq = QKp + (s & 15) * 768;
#pragma unroll
        for (int t = 0; t < T_; t++) {
            unsigned int word = *(const unsigned int*)&spkA[t * D_ + tid * 4];
            if (word) atomicOr(dstq + t * 192 + tid, word);
        }
    }
}

// ---------------------------------------------------------------------------
// 6) Final BatchNorm1d (fp64 stats), register-resident, float4 in/out.
//    (R1: faster than LDS-tile scalar version.)
// ---------------------------------------------------------------------------
__global__ __launch_bounds__(256) void k_bn_out(const float* __restrict__ Xin,
                                                float* __restrict__ out) {
    int s = blockIdx.x;
    __shared__ double red[4][2];
    __shared__ double st[2];
    int tid = threadIdx.x;
    int lane = tid & 63, wv = tid >> 6;
    float4 vv[3];
    double sum = 0.0, sumsq = 0.0;
#pragma unroll
    for (int i = 0; i < 3; i++) {
        int idx = i * 256 + tid;
        int t = idx / 192, c = idx - t * 192;
        float4 v = *(const float4*)(
            Xin + (size_t)t * SD_ + (size_t)s * D_ + c * 4);
        vv[i] = v;
        sum += ((double)v.x + (double)v.y) + ((double)v.z + (double)v.w);
        sumsq += ((double)v.x * v.x + (double)v.y * v.y) +
                 ((double)v.z * v.z + (double)v.w * v.w);
    }
#pragma unroll
    for (int off = 32; off > 0; off >>= 1) {
        sum += __shfl_down(sum, off);
        sumsq += __shfl_down(sumsq, off);
    }
    if (lane == 0) { red[wv][0] = sum; red[wv][1] = sumsq; }
    __syncthreads();
    if (tid == 0) {
        double s4 = red[0][0] + red[1][0] + red[2][0] + red[3][0];
        double q4 = red[0][1] + red[1][1] + red[2][1] + red[3][1];
        double mean = s4 / 3072.0;
        double var = q4 / 3072.0 - mean * mean;
        st[0] = mean;
        st[1] = 1.0 / sqrt(var + 1e-5);
    }
    __syncthreads();
    double mean = st[0], rstd = st[1];
#pragma unroll
    for (int i = 0; i < 3; i++) {
        int idx = i * 256 + tid;
        int t = idx / 192, c = idx - t * 192;
        float4 o;
        o.x = (float)(((double)vv[i].x - mean) * rstd);
        o.y = (float)(((double)vv[i].y - mean) * rstd);
        o.z = (float)(((double)vv[i].z - mean) * rstd);
        o.w = (float)(((double)vv[i].w - mean) * rstd);
        *(float4*)(out + (size_t)t * SD_ + (size_t)s * D_ + c * 4) = o;
    }
}

// ---------------------------------------------------------------------------
extern "C" void kernel_launch(void* const* d_in, const int* in_sizes, int n_in,
                              void* d_out, int out_size, void* d_ws,
                              size_t ws_size, hipStream_t stream) {
    const float* x  = (const float*)d_in[0];
    const float* wq = (const float*)d_in[1];
    const float* wk = (const float*)d_in[2];
    const float* wv = (const float*)d_in[3];
    const float* wo = (const float*)d_in[4];
    float* out = (float*)d_out;

    float* ws  = (float*)d_ws;
    float* Qf  = ws;                         // pre-BN Q, then GEMM2 out
    float* Kf  = ws + (size_t)TSD_;
    float* Vf  = ws + (size_t)2 * TSD_;
    unsigned int* QKp = (unsigned int*)(ws + (size_t)3 * TSD_);  // 12288 words
    unsigned char* Sx = (unsigned char*)(QKp + 12288);  // init spikes (frag)
    unsigned char* Vs = Sx + (size_t)TSD_;
    unsigned char* Bp = Vs + (size_t)TSD_;   // packed weights, 9.4 MB

    // 0) pack weights + init spikes + zero QKp
    k_prep_all<<<dim3(576, 5), 256, 0, stream>>>(wq, wk, wv, wo, x, Bp, Sx,
                                                 QKp);
    // 1) Q/K/V GEMMs (A from global frag-order, B LDS dbuf BK=128)
    k_gemm_i8<<<dim3(64, 12, 3), 256, 0, stream>>>(Sx, Bp, nullptr,
                                                   Qf, Kf, Vf, 0);
    // 2) BN + IF for Q,K,V + q&k presence accumulation (one block per s)
    k_bnif_qk<<<S_, 256, 0, stream>>>(Qf, Kf, Vf, Vs, QKp);
    // 3) out_pre = (Vs & mask) @ wo -> Qf  (mask OR-reduced in prologue)
    k_gemm_i8<<<dim3(64, 12, 1), 256, 0, stream>>>(Vs, Bp, QKp, Qf, Qf, Qf, 3);
    // 4) final BN -> d_out
    k_bn_out<<<S_, 256, 0, stream>>>(Qf, out);
}